// Round 10
// baseline (183.439 us; speedup 1.0000x reference)
//
#include <hip/hip_runtime.h>
#include <hip/hip_bf16.h>
#include <math.h>

#define BATCH 32
#define TMEL  2048
#define TTEXT 512
#define DD    80    // attention channels
#define DP    96    // padded to 3 x 32 for MFMA K
#define NOUT  256
#define NK    256   // key/value input channels

typedef short bf16x8 __attribute__((ext_vector_type(8)));   // 8 bf16 (4 VGPRs)
typedef float f32x4  __attribute__((ext_vector_type(4)));
typedef int   i32x4  __attribute__((ext_vector_type(4)));
typedef unsigned short u16x4 __attribute__((ext_vector_type(4)));
typedef unsigned short u16x8 __attribute__((ext_vector_type(8)));

static __device__ __forceinline__ unsigned short f2b(float x) {
  __hip_bfloat16 h = __float2bfloat16(x);
  return __builtin_bit_cast(unsigned short, h);
}
static __device__ __forceinline__ float b2f(unsigned short h) {
  unsigned u = (unsigned)h << 16;
  return __builtin_bit_cast(float, u);
}
static __device__ __forceinline__ bf16x8 ldb(const unsigned short* p) {
  return *reinterpret_cast<const bf16x8*>(p);
}
// non-temporal 16B load (read-once streams: prior/queries/keys/values)
static __device__ __forceinline__ f32x4 ld_nt4(const float* p) {
  return __builtin_nontemporal_load(reinterpret_cast<const f32x4*>(p));
}
static __device__ __forceinline__ i32x4 ld_nti(const int* p) {
  return __builtin_nontemporal_load(reinterpret_cast<const i32x4*>(p));
}
// load 8 consecutive f32 (nt) and convert to a bf16x8 fragment
static __device__ __forceinline__ bf16x8 cvt8(const float* p) {
  f32x4 a = ld_nt4(p);
  f32x4 c = ld_nt4(p + 4);
  bf16x8 v;
  #pragma unroll
  for (int r = 0; r < 4; ++r) {
    v[r]     = (short)f2b(a[r]);
    v[r + 4] = (short)f2b(c[r]);
  }
  return v;
}
// streaming store: nt flag, no L2 retention (outputs are never re-read)
static __device__ __forceinline__ void st_nt(float* p, f32x4 v) {
  __builtin_nontemporal_store(v, reinterpret_cast<f32x4*>(p));
}

// Barrier that orders LDS only (no vmcnt drain): in-flight global stores
// keep draining under subsequent MFMA phases.
static __device__ __forceinline__ void barrier_lgkm() {
  asm volatile("s_waitcnt lgkmcnt(0)" ::: "memory");
  __builtin_amdgcn_s_barrier();
  __builtin_amdgcn_sched_barrier(0);
}

// ---------------- weight prep: all W -> bf16, transposed, padded ----------------
__global__ __launch_bounds__(256) void prep_w_kernel(
    const float* __restrict__ Wq, const float* __restrict__ Wk,
    const float* __restrict__ Wv, const float* __restrict__ Wo,
    unsigned short* __restrict__ Wqt, unsigned short* __restrict__ Wkt,
    unsigned short* __restrict__ Wvt, unsigned short* __restrict__ Wot)
{
  int i = blockIdx.x * 256 + threadIdx.x;
  if (i < DD * DP) {              // Wqt[d][k], k padded to 96
    int d = i / DP, k = i - d * DP;
    Wqt[i] = (k < DD) ? f2b(Wq[k * DD + d]) : (unsigned short)0;
  }
  if (i < DD * NK) {              // Wkt[d][k], Wvt[d][k], k = 256 exact
    int d = i / NK, k = i - d * NK;
    Wkt[i] = f2b(Wk[(size_t)k * DD + d]);
    Wvt[i] = f2b(Wv[(size_t)k * DD + d]);
  }
  if (i < NOUT * DP) {            // Wot[n][k], k padded to 96
    int n = i / DP, k = i - n * DP;
    Wot[i] = (k < DD) ? f2b(Wo[(size_t)k * NOUT + n]) : (unsigned short)0;
  }
}

// ---------------- K/V projection: split blocks (halved serial chain, 2x TLP) ----------------
// blocks [0,1024): K path; blocks [1024,2048): V path. 1 wave = 16 text rows.
// inv_scale = 1/sqrt(DD): BOTH q and k scale factors folded into K'.
__global__ __launch_bounds__(64) void proj_kv_kernel(
    const float* __restrict__ keys, const float* __restrict__ values,
    const unsigned short* __restrict__ Wkt, const unsigned short* __restrict__ Wvt,
    const float* __restrict__ bk, const float* __restrict__ bv,
    unsigned short* __restrict__ Kp, unsigned short* __restrict__ Vt, float inv_scale)
{
  const int lane = threadIdx.x, lhi = lane >> 4, llo = lane & 15;
  const int gid = blockIdx.x;
  const bool isK = gid < (BATCH * TTEXT / 16);
  const size_t row0 = (size_t)(isK ? gid : gid - BATCH * TTEXT / 16) * 16;
  const int b = (int)(row0 >> 9);
  const int t = (int)(row0 & 511) + llo;

  if (isK) {
    const float* Kr = keys + (row0 + llo) * NK;
    bf16x8 xf[8];
    #pragma unroll
    for (int ks = 0; ks < 8; ++ks) xf[ks] = cvt8(Kr + ks * 32 + lhi * 8);
    f32x4 acc[5] = {};
    #pragma unroll
    for (int dt = 0; dt < 5; ++dt) {
      const unsigned short* Wr = Wkt + (dt * 16 + llo) * NK + lhi * 8;
      #pragma unroll
      for (int ks = 0; ks < 8; ++ks)
        acc[dt] = __builtin_amdgcn_mfma_f32_16x16x32_bf16(ldb(Wr + ks * 32), xf[ks], acc[dt], 0, 0, 0);
    }
    unsigned short* Krow = Kp + (row0 + llo) * DP;
    #pragma unroll
    for (int dt = 0; dt < 5; ++dt) {
      f32x4 b4 = *reinterpret_cast<const f32x4*>(bk + dt * 16 + lhi * 4);
      u16x4 h4;
      #pragma unroll
      for (int r = 0; r < 4; ++r) h4[r] = f2b((acc[dt][r] + b4[r]) * inv_scale);
      *reinterpret_cast<u16x4*>(Krow + dt * 16 + lhi * 4) = h4;
    }
    if (lhi == 0) {
      u16x8 z8 = {};
      *reinterpret_cast<u16x8*>(Krow + 80) = z8;
      *reinterpret_cast<u16x8*>(Krow + 88) = z8;
    }
  } else {
    const float* Vr = values + (row0 + llo) * NK;
    bf16x8 xf[8];
    #pragma unroll
    for (int ks = 0; ks < 8; ++ks) xf[ks] = cvt8(Vr + ks * 32 + lhi * 8);
    f32x4 acc[5] = {};
    #pragma unroll
    for (int dt = 0; dt < 5; ++dt) {
      const unsigned short* Wr = Wvt + (dt * 16 + llo) * NK + lhi * 8;
      #pragma unroll
      for (int ks = 0; ks < 8; ++ks)
        acc[dt] = __builtin_amdgcn_mfma_f32_16x16x32_bf16(ldb(Wr + ks * 32), xf[ks], acc[dt], 0, 0, 0);
    }
    #pragma unroll
    for (int dt = 0; dt < 5; ++dt) {
      f32x4 b4 = *reinterpret_cast<const f32x4*>(bv + dt * 16 + lhi * 4);
      #pragma unroll
      for (int r = 0; r < 4; ++r) {
        int d = dt * 16 + lhi * 4 + r;
        Vt[((size_t)b * DD + d) * TTEXT + t] = f2b(acc[dt][r] + b4[r]);
      }
    }
  }
}

// ---------------- fused attention: 512 threads / 8 waves, 32 mel rows ----------------
// 1-D grid 2048 with XCD swizzle: id_sw = (id&7)*256 + id>>3 gives each XCD
// 256 consecutive work-units = 4 whole batches -> Kp/Vt/Wqt/Wot stay L2-local
// per XCD instead of being refetched by all 8. Q-projection fused; per-wave
// vmem discipline (all loads before any store); role-split at barrier-2;
// out0 staged in LDS (swizzled) and streamed coalesced.
// LDS aliasing timeline on s_attn: [s_q: start..b1) [attn: b1..b3) [s_o: b3..end]
__global__ __launch_bounds__(512, 4) void attn_main_kernel(
    const float* __restrict__ queries, const unsigned short* __restrict__ Wqt,
    const float* __restrict__ bq,
    const float* __restrict__ prior, const int* __restrict__ mask,
    const unsigned short* __restrict__ Kp,
    const unsigned short* __restrict__ Vt, const unsigned short* __restrict__ Wot,
    const float* __restrict__ bo,
    float* __restrict__ out0, float* __restrict__ out1, float* __restrict__ out2)
{
  __shared__ __align__(16) unsigned short s_attn[32][520];  // 33,280 B
  __shared__ __align__(16) unsigned short s_cbf[32][96];    //  6,144 B (also s_red)
  float (*s_red)[8][32] = reinterpret_cast<float(*)[8][32]>(&s_cbf[0][0]); // 2KB alias
  unsigned short (*s_q)[104] = reinterpret_cast<unsigned short(*)[104]>(&s_attn[0][0]); // 6,656B alias
  float* s_o = reinterpret_cast<float*>(&s_attn[0][0]);     // 32,768B alias (out0 tile)

  const int tid = threadIdx.x, w = tid >> 6, lane = tid & 63, lhi = lane >> 4, llo = lane & 15;
  const int id = blockIdx.x;
  const int id_sw = (id & 7) * 256 + (id >> 3);   // XCD-contiguous batches
  const int b = id_sw >> 6, m0 = (id_sw & 63) * 32;
  const int tb = w * 64;

  // ---- Wot fragments hoisted to registers (L2-hot): proj does no vmem loads ----
  const int n0 = w * 32;
  bf16x8 wf[2][3];
  #pragma unroll
  for (int nt = 0; nt < 2; ++nt)
    #pragma unroll
    for (int ks = 0; ks < 3; ++ks)
      wf[nt][ks] = ldb(Wot + (size_t)(n0 + nt * 16 + llo) * DP + ks * 32 + lhi * 8);

  // ---- fused Q-projection: 10 units (rowgrp x dt) over 8 waves, staged in s_q ----
  for (int j = w; j < 10; j += 8) {
    const int rowgrp = j / 5, dt = j % 5;
    const float* Xr = queries + ((size_t)b * TMEL + m0 + rowgrp * 16 + llo) * DD;
    bf16x8 xf0 = cvt8(Xr + lhi * 8);
    bf16x8 xf1 = cvt8(Xr + 32 + lhi * 8);
    bf16x8 xf2 = {};
    if (lhi < 2) xf2 = cvt8(Xr + 64 + lhi * 8);   // k 64..80 valid; 80..96 zero
    const unsigned short* Wr = Wqt + (dt * 16 + llo) * DP + lhi * 8;
    f32x4 acc = {};
    acc = __builtin_amdgcn_mfma_f32_16x16x32_bf16(ldb(Wr),      xf0, acc, 0, 0, 0);
    acc = __builtin_amdgcn_mfma_f32_16x16x32_bf16(ldb(Wr + 32), xf1, acc, 0, 0, 0);
    acc = __builtin_amdgcn_mfma_f32_16x16x32_bf16(ldb(Wr + 64), xf2, acc, 0, 0, 0);
    f32x4 b4 = *reinterpret_cast<const f32x4*>(bq + dt * 16 + lhi * 4);
    u16x4 h4;
    #pragma unroll
    for (int r = 0; r < 4; ++r) h4[r] = f2b(acc[r] + b4[r]);   // scale folded into K
    *reinterpret_cast<u16x4*>(&s_q[rowgrp * 16 + llo][dt * 16 + lhi * 4]) = h4;
  }
  s_q[tid >> 4][DD + (tid & 15)] = 0;   // zero pad cols 80..95

  // ---- z init = mask/log-prior (nt loads; issue early, overlap MFMAs) ----
  f32x4 z[2][4];
  #pragma unroll
  for (int tt = 0; tt < 4; ++tt) {
    const int t0 = tb + tt * 16 + lhi * 4;
    i32x4 mk4 = ld_nti(&mask[(size_t)b * TTEXT + t0]);
    #pragma unroll
    for (int mt = 0; mt < 2; ++mt) {
      f32x4 p4 = ld_nt4(&prior[((size_t)b * TMEL + m0 + mt * 16 + llo) * TTEXT + t0]);
      #pragma unroll
      for (int r = 0; r < 4; ++r)
        z[mt][tt][r] = mk4[r] ? __logf(p4[r] + 1e-8f) : -INFINITY;
    }
  }

  barrier_lgkm();   // barrier 0: s_q visible

  // ---- Q fragments from LDS ----
  bf16x8 qa[2][3];
  #pragma unroll
  for (int mt = 0; mt < 2; ++mt)
    #pragma unroll
    for (int ks = 0; ks < 3; ++ks)
      qa[mt][ks] = ldb(&s_q[mt * 16 + llo][ks * 32 + lhi * 8]);

  // ---- scores accumulate onto log-prior ----
  const unsigned short* Kb = Kp + (size_t)b * TTEXT * DP;
  #pragma unroll
  for (int tt = 0; tt < 4; ++tt) {
    int t0 = tb + tt * 16;
    #pragma unroll
    for (int ks = 0; ks < 3; ++ks) {
      bf16x8 kf = ldb(Kb + (size_t)(t0 + llo) * DP + ks * 32 + lhi * 8);
      #pragma unroll
      for (int mt = 0; mt < 2; ++mt)
        z[mt][tt] = __builtin_amdgcn_mfma_f32_16x16x32_bf16(kf, qa[mt][ks], z[mt][tt], 0, 0, 0);
    }
  }

  // ---- wave-local softmax stats ----
  float mw[2] = {-INFINITY, -INFINITY};
  #pragma unroll
  for (int tt = 0; tt < 4; ++tt)
    #pragma unroll
    for (int mt = 0; mt < 2; ++mt)
      #pragma unroll
      for (int r = 0; r < 4; ++r) mw[mt] = fmaxf(mw[mt], z[mt][tt][r]);
  #pragma unroll
  for (int mt = 0; mt < 2; ++mt) {
    mw[mt] = fmaxf(mw[mt], __shfl_xor(mw[mt], 16));
    mw[mt] = fmaxf(mw[mt], __shfl_xor(mw[mt], 32));
  }
  float sw[2] = {0.f, 0.f};
  #pragma unroll
  for (int tt = 0; tt < 4; ++tt)
    #pragma unroll
    for (int mt = 0; mt < 2; ++mt)
      #pragma unroll
      for (int r = 0; r < 4; ++r) {
        float e = __expf(z[mt][tt][r] - mw[mt]);
        z[mt][tt][r] = e;
        sw[mt] += e;
      }
  #pragma unroll
  for (int mt = 0; mt < 2; ++mt) {
    sw[mt] += __shfl_xor(sw[mt], 16);
    sw[mt] += __shfl_xor(sw[mt], 32);
  }
  if (lane < 16) {
    s_red[0][w][llo] = mw[0];  s_red[0][w][16 + llo] = mw[1];
    s_red[1][w][llo] = sw[0];  s_red[1][w][16 + llo] = sw[1];
  }
  barrier_lgkm();   // barrier 1: s_red visible; s_q dead

  float fac[2];
  #pragma unroll
  for (int mt = 0; mt < 2; ++mt) {
    const int idx = mt * 16 + llo;
    float M = s_red[0][0][idx];
    #pragma unroll
    for (int v = 1; v < 8; ++v) M = fmaxf(M, s_red[0][v][idx]);
    float L = 0.f;
    #pragma unroll
    for (int v = 0; v < 8; ++v) L += s_red[1][v][idx] * __expf(s_red[0][v][idx] - M);
    fac[mt] = __expf(mw[mt] - M) / L;
  }

  // ---- normalize; stage bf16 to LDS ----
  #pragma unroll
  for (int tt = 0; tt < 4; ++tt) {
    const int t0 = tb + tt * 16 + lhi * 4;
    #pragma unroll
    for (int mt = 0; mt < 2; ++mt) {
      u16x4 h4;
      #pragma unroll
      for (int r = 0; r < 4; ++r) h4[r] = f2b(z[mt][tt][r] * fac[mt]);
      *reinterpret_cast<u16x4*>(&s_attn[mt * 16 + llo][t0]) = h4;
    }
  }
  barrier_lgkm();   // barrier 2: s_attn visible; s_red dead

  // ---- zero pad cols of s_cbf (80..95) ----
  s_cbf[tid >> 4][DD + (tid & 15)] = 0;

  if (w < 5) {
    // ---- PV: wave w owns dt=w for both mt; full K=512 ----
    const unsigned short* Vb = Vt + (size_t)b * DD * TTEXT;
    #pragma unroll
    for (int mt = 0; mt < 2; ++mt) {
      f32x4 pv = {};
      #pragma unroll
      for (int ks = 0; ks < 16; ++ks) {
        bf16x8 af = ldb(&s_attn[mt * 16 + llo][ks * 32 + lhi * 8]);
        bf16x8 vf = ldb(Vb + (size_t)(w * 16 + llo) * TTEXT + ks * 32 + lhi * 8);
        pv = __builtin_amdgcn_mfma_f32_16x16x32_bf16(af, vf, pv, 0, 0, 0);
      }
      #pragma unroll
      for (int r = 0; r < 4; ++r)
        s_cbf[mt * 16 + lhi * 4 + r][w * 16 + llo] = f2b(pv[r]);
    }
  } else {
    // ---- store waves: stream out1/out2 from LDS, fully-coalesced nt stores ----
    const size_t obase = ((size_t)b * TMEL + m0) * TTEXT;
    const int sid = (w - 5) * 64 + lane;           // 0..191
    for (int c = sid; c < 4096; c += 192) {        // f32x4 chunks over 32x512 tile
      const int row = c >> 7, col = (c & 127) << 2;
      u16x4 h4 = *reinterpret_cast<const u16x4*>(&s_attn[row][col]);
      f32x4 a4;
      #pragma unroll
      for (int r = 0; r < 4; ++r) a4[r] = b2f(h4[r]);
      const size_t o = obase + (size_t)row * TTEXT + col;
      st_nt(&out1[o], a4);
      st_nt(&out2[o], a4);
    }
  }
  barrier_lgkm();   // barrier 3: s_cbf visible; s_attn dead (s_o lives here now)

  // ---- output projection: ds_read + register wf only (no vmem loads) ----
  bf16x8 ca[2][3];
  #pragma unroll
  for (int mt = 0; mt < 2; ++mt)
    #pragma unroll
    for (int ks = 0; ks < 3; ++ks)
      ca[mt][ks] = ldb(&s_cbf[mt * 16 + llo][ks * 32 + lhi * 8]);

  #pragma unroll
  for (int nt = 0; nt < 2; ++nt) {
    f32x4 oo[2] = {};
    #pragma unroll
    for (int ks = 0; ks < 3; ++ks) {
      #pragma unroll
      for (int mt = 0; mt < 2; ++mt)
        oo[mt] = __builtin_amdgcn_mfma_f32_16x16x32_bf16(wf[nt][ks], ca[mt][ks], oo[mt], 0, 0, 0);
    }
    f32x4 bo4 = *reinterpret_cast<const f32x4*>(&bo[n0 + nt * 16 + lhi * 4]);
    #pragma unroll
    for (int mt = 0; mt < 2; ++mt) {
      const int row = mt * 16 + llo;
      const int chunk = (w * 8 + nt * 4 + lhi) ^ (row & 7);   // swizzled 16B chunk
      f32x4 res;
      #pragma unroll
      for (int r = 0; r < 4; ++r) res[r] = oo[mt][r] + bo4[r];
      *reinterpret_cast<f32x4*>(&s_o[row * NOUT + chunk * 4]) = res;
    }
  }
  barrier_lgkm();   // barrier 4: s_o visible

  // ---- out0 from LDS, linear order: 1KB fully-coalesced nt stores ----
  const size_t obase0 = ((size_t)b * TMEL + m0) * NOUT;
  #pragma unroll
  for (int it = 0; it < 4; ++it) {
    const int c = tid + it * 512;          // 16B chunk id over 32x256 f32 tile
    const int row = c >> 6, chunk = c & 63;
    const int chunk_sw = chunk ^ (row & 7);
    f32x4 v = *reinterpret_cast<const f32x4*>(&s_o[row * NOUT + chunk_sw * 4]);
    st_nt(&out0[obase0 + (size_t)row * NOUT + chunk * 4], v);
  }
}

extern "C" void kernel_launch(void* const* d_in, const int* in_sizes, int n_in,
                              void* d_out, int out_size, void* d_ws, size_t ws_size,
                              hipStream_t stream)
{
  (void)in_sizes; (void)n_in; (void)out_size; (void)ws_size;
  const float* queries = (const float*)d_in[0];
  const float* keys    = (const float*)d_in[1];
  const float* values  = (const float*)d_in[2];
  const int*   mask    = (const int*)d_in[3];   // bool input -> int32 on device
  const float* prior   = (const float*)d_in[4];
  const float* Wq = (const float*)d_in[5];
  const float* bq = (const float*)d_in[6];
  const float* Wk = (const float*)d_in[7];
  const float* bk = (const float*)d_in[8];
  const float* Wv = (const float*)d_in[9];
  const float* bv = (const float*)d_in[10];
  const float* Wo = (const float*)d_in[11];
  const float* bo = (const float*)d_in[12];

  float* out0 = (float*)d_out;
  float* out1 = out0 + (size_t)BATCH * TMEL * NOUT;
  float* out2 = out1 + (size_t)BATCH * TMEL * TTEXT;

  unsigned short* Kp  = (unsigned short*)d_ws;
  unsigned short* Vt  = Kp  + (size_t)BATCH * TTEXT * DP;
  unsigned short* Wqt = Vt  + (size_t)BATCH * DD * TTEXT;
  unsigned short* Wkt = Wqt + (size_t)DD * DP;
  unsigned short* Wvt = Wkt + (size_t)DD * NK;
  unsigned short* Wot = Wvt + (size_t)DD * NK;

  const float inv_scale = 1.0f / sqrtf((float)DD);   // both q,k scales folded into K

  prep_w_kernel<<<dim3((NOUT * DP + 255) / 256), 256, 0, stream>>>(
      Wq, Wk, Wv, Wo, Wqt, Wkt, Wvt, Wot);
  proj_kv_kernel<<<dim3(2 * BATCH * TTEXT / 16), 64, 0, stream>>>(
      keys, values, Wkt, Wvt, bk, bv, Kp, Vt, inv_scale);
  attn_main_kernel<<<dim3(TMEL / 32 * BATCH), 512, 0, stream>>>(
      queries, Wqt, bq, prior, mask, Kp, Vt, Wot, bo, out0, out1, out2);
}

// Round 11
// 119.084 us; speedup vs baseline: 1.5404x; 1.5404x over previous
//
#include <hip/hip_runtime.h>
#include <hip/hip_bf16.h>
#include <math.h>

#define BATCH 32
#define TMEL  2048
#define TTEXT 512
#define DD    80    // attention channels
#define DP    96    // padded to 3 x 32 for MFMA K
#define NOUT  256
#define NK    256   // key/value input channels

typedef short bf16x8 __attribute__((ext_vector_type(8)));   // 8 bf16 (4 VGPRs)
typedef float f32x4  __attribute__((ext_vector_type(4)));
typedef int   i32x4  __attribute__((ext_vector_type(4)));
typedef unsigned short u16x4 __attribute__((ext_vector_type(4)));
typedef unsigned short u16x8 __attribute__((ext_vector_type(8)));

static __device__ __forceinline__ unsigned short f2b(float x) {
  __hip_bfloat16 h = __float2bfloat16(x);
  return __builtin_bit_cast(unsigned short, h);
}
static __device__ __forceinline__ float b2f(unsigned short h) {
  unsigned u = (unsigned)h << 16;
  return __builtin_bit_cast(float, u);
}
static __device__ __forceinline__ bf16x8 ldb(const unsigned short* p) {
  return *reinterpret_cast<const bf16x8*>(p);
}
// load 8 consecutive f32 and convert to a bf16x8 fragment
static __device__ __forceinline__ bf16x8 cvt8(const float* p) {
  f32x4 a = *reinterpret_cast<const f32x4*>(p);
  f32x4 c = *reinterpret_cast<const f32x4*>(p + 4);
  bf16x8 v;
  #pragma unroll
  for (int r = 0; r < 4; ++r) {
    v[r]     = (short)f2b(a[r]);
    v[r + 4] = (short)f2b(c[r]);
  }
  return v;
}
// streaming store: nt flag, no L2 retention (outputs are never re-read)
static __device__ __forceinline__ void st_nt(float* p, f32x4 v) {
  __builtin_nontemporal_store(v, reinterpret_cast<f32x4*>(p));
}

// Barrier that orders LDS only (no vmcnt drain): in-flight global stores
// keep draining under subsequent MFMA phases.
static __device__ __forceinline__ void barrier_lgkm() {
  asm volatile("s_waitcnt lgkmcnt(0)" ::: "memory");
  __builtin_amdgcn_s_barrier();
  __builtin_amdgcn_sched_barrier(0);
}

// ---------------- weight prep: all W -> bf16, transposed, padded ----------------
__global__ __launch_bounds__(256) void prep_w_kernel(
    const float* __restrict__ Wq, const float* __restrict__ Wk,
    const float* __restrict__ Wv, const float* __restrict__ Wo,
    unsigned short* __restrict__ Wqt, unsigned short* __restrict__ Wkt,
    unsigned short* __restrict__ Wvt, unsigned short* __restrict__ Wot)
{
  int i = blockIdx.x * 256 + threadIdx.x;
  if (i < DD * DP) {              // Wqt[d][k], k padded to 96
    int d = i / DP, k = i - d * DP;
    Wqt[i] = (k < DD) ? f2b(Wq[k * DD + d]) : (unsigned short)0;
  }
  if (i < DD * NK) {              // Wkt[d][k], Wvt[d][k], k = 256 exact
    int d = i / NK, k = i - d * NK;
    Wkt[i] = f2b(Wk[(size_t)k * DD + d]);
    Wvt[i] = f2b(Wv[(size_t)k * DD + d]);
  }
  if (i < NOUT * DP) {            // Wot[n][k], k padded to 96
    int n = i / DP, k = i - n * DP;
    Wot[i] = (k < DD) ? f2b(Wo[(size_t)k * NOUT + n]) : (unsigned short)0;
  }
}

// ---------------- K/V projection: split blocks (halved serial chain, 2x TLP) ----------------
// blocks [0,1024): K path; blocks [1024,2048): V path. 1 wave = 16 text rows.
// inv_scale = 1/sqrt(DD): BOTH q and k scale factors folded into K'.
__global__ __launch_bounds__(64) void proj_kv_kernel(
    const float* __restrict__ keys, const float* __restrict__ values,
    const unsigned short* __restrict__ Wkt, const unsigned short* __restrict__ Wvt,
    const float* __restrict__ bk, const float* __restrict__ bv,
    unsigned short* __restrict__ Kp, unsigned short* __restrict__ Vt, float inv_scale)
{
  const int lane = threadIdx.x, lhi = lane >> 4, llo = lane & 15;
  const int gid = blockIdx.x;
  const bool isK = gid < (BATCH * TTEXT / 16);
  const size_t row0 = (size_t)(isK ? gid : gid - BATCH * TTEXT / 16) * 16;
  const int b = (int)(row0 >> 9);
  const int t = (int)(row0 & 511) + llo;

  if (isK) {
    const float* Kr = keys + (row0 + llo) * NK;
    bf16x8 xf[8];
    #pragma unroll
    for (int ks = 0; ks < 8; ++ks) xf[ks] = cvt8(Kr + ks * 32 + lhi * 8);
    f32x4 acc[5] = {};
    #pragma unroll
    for (int dt = 0; dt < 5; ++dt) {
      const unsigned short* Wr = Wkt + (dt * 16 + llo) * NK + lhi * 8;
      #pragma unroll
      for (int ks = 0; ks < 8; ++ks)
        acc[dt] = __builtin_amdgcn_mfma_f32_16x16x32_bf16(ldb(Wr + ks * 32), xf[ks], acc[dt], 0, 0, 0);
    }
    unsigned short* Krow = Kp + (row0 + llo) * DP;
    #pragma unroll
    for (int dt = 0; dt < 5; ++dt) {
      f32x4 b4 = *reinterpret_cast<const f32x4*>(bk + dt * 16 + lhi * 4);
      u16x4 h4;
      #pragma unroll
      for (int r = 0; r < 4; ++r) h4[r] = f2b((acc[dt][r] + b4[r]) * inv_scale);
      *reinterpret_cast<u16x4*>(Krow + dt * 16 + lhi * 4) = h4;
    }
    if (lhi == 0) {
      u16x8 z8 = {};
      *reinterpret_cast<u16x8*>(Krow + 80) = z8;
      *reinterpret_cast<u16x8*>(Krow + 88) = z8;
    }
  } else {
    const float* Vr = values + (row0 + llo) * NK;
    bf16x8 xf[8];
    #pragma unroll
    for (int ks = 0; ks < 8; ++ks) xf[ks] = cvt8(Vr + ks * 32 + lhi * 8);
    f32x4 acc[5] = {};
    #pragma unroll
    for (int dt = 0; dt < 5; ++dt) {
      const unsigned short* Wr = Wvt + (dt * 16 + llo) * NK + lhi * 8;
      #pragma unroll
      for (int ks = 0; ks < 8; ++ks)
        acc[dt] = __builtin_amdgcn_mfma_f32_16x16x32_bf16(ldb(Wr + ks * 32), xf[ks], acc[dt], 0, 0, 0);
    }
    #pragma unroll
    for (int dt = 0; dt < 5; ++dt) {
      f32x4 b4 = *reinterpret_cast<const f32x4*>(bv + dt * 16 + lhi * 4);
      #pragma unroll
      for (int r = 0; r < 4; ++r) {
        int d = dt * 16 + lhi * 4 + r;
        Vt[((size_t)b * DD + d) * TTEXT + t] = f2b(acc[dt][r] + b4[r]);
      }
    }
  }
}

// ---------------- fused attention: 512 threads / 8 waves, 32 mel rows ----------------
// (R9 structure: natural 2-D grid dispatch order preserves streaming locality;
// no nt LOADS — nt is for the write streams only.)
// Q-projection fused; per-wave vmem discipline (all loads before any store);
// role-split at barrier-2: waves 0-4 PV, waves 5-7 stream out1/out2;
// out0 staged in LDS (swizzled) and streamed coalesced.
// LDS aliasing timeline on s_attn: [s_q: start..b1) [attn: b1..b3) [s_o: b3..end]
__global__ __launch_bounds__(512, 4) void attn_main_kernel(
    const float* __restrict__ queries, const unsigned short* __restrict__ Wqt,
    const float* __restrict__ bq,
    const float* __restrict__ prior, const int* __restrict__ mask,
    const unsigned short* __restrict__ Kp,
    const unsigned short* __restrict__ Vt, const unsigned short* __restrict__ Wot,
    const float* __restrict__ bo,
    float* __restrict__ out0, float* __restrict__ out1, float* __restrict__ out2)
{
  __shared__ __align__(16) unsigned short s_attn[32][520];  // 33,280 B
  __shared__ __align__(16) unsigned short s_cbf[32][96];    //  6,144 B (also s_red)
  float (*s_red)[8][32] = reinterpret_cast<float(*)[8][32]>(&s_cbf[0][0]); // 2KB alias
  unsigned short (*s_q)[104] = reinterpret_cast<unsigned short(*)[104]>(&s_attn[0][0]); // 6,656B alias
  float* s_o = reinterpret_cast<float*>(&s_attn[0][0]);     // 32,768B alias (out0 tile)

  const int tid = threadIdx.x, w = tid >> 6, lane = tid & 63, lhi = lane >> 4, llo = lane & 15;
  const int b = blockIdx.y, m0 = blockIdx.x * 32;
  const int tb = w * 64;

  // ---- Wot fragments hoisted to registers (L2-hot): proj does no vmem loads ----
  const int n0 = w * 32;
  bf16x8 wf[2][3];
  #pragma unroll
  for (int nt = 0; nt < 2; ++nt)
    #pragma unroll
    for (int ks = 0; ks < 3; ++ks)
      wf[nt][ks] = ldb(Wot + (size_t)(n0 + nt * 16 + llo) * DP + ks * 32 + lhi * 8);

  // ---- fused Q-projection: 10 units (rowgrp x dt) over 8 waves, staged in s_q ----
  for (int j = w; j < 10; j += 8) {
    const int rowgrp = j / 5, dt = j % 5;
    const float* Xr = queries + ((size_t)b * TMEL + m0 + rowgrp * 16 + llo) * DD;
    bf16x8 xf0 = cvt8(Xr + lhi * 8);
    bf16x8 xf1 = cvt8(Xr + 32 + lhi * 8);
    bf16x8 xf2 = {};
    if (lhi < 2) xf2 = cvt8(Xr + 64 + lhi * 8);   // k 64..80 valid; 80..96 zero
    const unsigned short* Wr = Wqt + (dt * 16 + llo) * DP + lhi * 8;
    f32x4 acc = {};
    acc = __builtin_amdgcn_mfma_f32_16x16x32_bf16(ldb(Wr),      xf0, acc, 0, 0, 0);
    acc = __builtin_amdgcn_mfma_f32_16x16x32_bf16(ldb(Wr + 32), xf1, acc, 0, 0, 0);
    acc = __builtin_amdgcn_mfma_f32_16x16x32_bf16(ldb(Wr + 64), xf2, acc, 0, 0, 0);
    f32x4 b4 = *reinterpret_cast<const f32x4*>(bq + dt * 16 + lhi * 4);
    u16x4 h4;
    #pragma unroll
    for (int r = 0; r < 4; ++r) h4[r] = f2b(acc[r] + b4[r]);   // scale folded into K
    *reinterpret_cast<u16x4*>(&s_q[rowgrp * 16 + llo][dt * 16 + lhi * 4]) = h4;
  }
  s_q[tid >> 4][DD + (tid & 15)] = 0;   // zero pad cols 80..95

  // ---- z init = mask/log-prior (loads issue early, overlap MFMAs) ----
  f32x4 z[2][4];
  #pragma unroll
  for (int tt = 0; tt < 4; ++tt) {
    const int t0 = tb + tt * 16 + lhi * 4;
    i32x4 mk4 = *reinterpret_cast<const i32x4*>(&mask[(size_t)b * TTEXT + t0]);
    #pragma unroll
    for (int mt = 0; mt < 2; ++mt) {
      f32x4 p4 = *reinterpret_cast<const f32x4*>(
          &prior[((size_t)b * TMEL + m0 + mt * 16 + llo) * TTEXT + t0]);
      #pragma unroll
      for (int r = 0; r < 4; ++r)
        z[mt][tt][r] = mk4[r] ? __logf(p4[r] + 1e-8f) : -INFINITY;
    }
  }

  barrier_lgkm();   // barrier 0: s_q visible

  // ---- Q fragments from LDS ----
  bf16x8 qa[2][3];
  #pragma unroll
  for (int mt = 0; mt < 2; ++mt)
    #pragma unroll
    for (int ks = 0; ks < 3; ++ks)
      qa[mt][ks] = ldb(&s_q[mt * 16 + llo][ks * 32 + lhi * 8]);

  // ---- scores accumulate onto log-prior ----
  const unsigned short* Kb = Kp + (size_t)b * TTEXT * DP;
  #pragma unroll
  for (int tt = 0; tt < 4; ++tt) {
    int t0 = tb + tt * 16;
    #pragma unroll
    for (int ks = 0; ks < 3; ++ks) {
      bf16x8 kf = ldb(Kb + (size_t)(t0 + llo) * DP + ks * 32 + lhi * 8);
      #pragma unroll
      for (int mt = 0; mt < 2; ++mt)
        z[mt][tt] = __builtin_amdgcn_mfma_f32_16x16x32_bf16(kf, qa[mt][ks], z[mt][tt], 0, 0, 0);
    }
  }

  // ---- wave-local softmax stats ----
  float mw[2] = {-INFINITY, -INFINITY};
  #pragma unroll
  for (int tt = 0; tt < 4; ++tt)
    #pragma unroll
    for (int mt = 0; mt < 2; ++mt)
      #pragma unroll
      for (int r = 0; r < 4; ++r) mw[mt] = fmaxf(mw[mt], z[mt][tt][r]);
  #pragma unroll
  for (int mt = 0; mt < 2; ++mt) {
    mw[mt] = fmaxf(mw[mt], __shfl_xor(mw[mt], 16));
    mw[mt] = fmaxf(mw[mt], __shfl_xor(mw[mt], 32));
  }
  float sw[2] = {0.f, 0.f};
  #pragma unroll
  for (int tt = 0; tt < 4; ++tt)
    #pragma unroll
    for (int mt = 0; mt < 2; ++mt)
      #pragma unroll
      for (int r = 0; r < 4; ++r) {
        float e = __expf(z[mt][tt][r] - mw[mt]);
        z[mt][tt][r] = e;
        sw[mt] += e;
      }
  #pragma unroll
  for (int mt = 0; mt < 2; ++mt) {
    sw[mt] += __shfl_xor(sw[mt], 16);
    sw[mt] += __shfl_xor(sw[mt], 32);
  }
  if (lane < 16) {
    s_red[0][w][llo] = mw[0];  s_red[0][w][16 + llo] = mw[1];
    s_red[1][w][llo] = sw[0];  s_red[1][w][16 + llo] = sw[1];
  }
  barrier_lgkm();   // barrier 1: s_red visible; s_q dead

  float fac[2];
  #pragma unroll
  for (int mt = 0; mt < 2; ++mt) {
    const int idx = mt * 16 + llo;
    float M = s_red[0][0][idx];
    #pragma unroll
    for (int v = 1; v < 8; ++v) M = fmaxf(M, s_red[0][v][idx]);
    float L = 0.f;
    #pragma unroll
    for (int v = 0; v < 8; ++v) L += s_red[1][v][idx] * __expf(s_red[0][v][idx] - M);
    fac[mt] = __expf(mw[mt] - M) / L;
  }

  // ---- normalize; stage bf16 to LDS ----
  #pragma unroll
  for (int tt = 0; tt < 4; ++tt) {
    const int t0 = tb + tt * 16 + lhi * 4;
    #pragma unroll
    for (int mt = 0; mt < 2; ++mt) {
      u16x4 h4;
      #pragma unroll
      for (int r = 0; r < 4; ++r) h4[r] = f2b(z[mt][tt][r] * fac[mt]);
      *reinterpret_cast<u16x4*>(&s_attn[mt * 16 + llo][t0]) = h4;
    }
  }
  barrier_lgkm();   // barrier 2: s_attn visible; s_red dead

  // ---- zero pad cols of s_cbf (80..95) ----
  s_cbf[tid >> 4][DD + (tid & 15)] = 0;

  if (w < 5) {
    // ---- PV: wave w owns dt=w for both mt; full K=512 ----
    const unsigned short* Vb = Vt + (size_t)b * DD * TTEXT;
    #pragma unroll
    for (int mt = 0; mt < 2; ++mt) {
      f32x4 pv = {};
      #pragma unroll
      for (int ks = 0; ks < 16; ++ks) {
        bf16x8 af = ldb(&s_attn[mt * 16 + llo][ks * 32 + lhi * 8]);
        bf16x8 vf = ldb(Vb + (size_t)(w * 16 + llo) * TTEXT + ks * 32 + lhi * 8);
        pv = __builtin_amdgcn_mfma_f32_16x16x32_bf16(af, vf, pv, 0, 0, 0);
      }
      #pragma unroll
      for (int r = 0; r < 4; ++r)
        s_cbf[mt * 16 + lhi * 4 + r][w * 16 + llo] = f2b(pv[r]);
    }
  } else {
    // ---- store waves: stream out1/out2 from LDS, fully-coalesced nt stores ----
    const size_t obase = ((size_t)b * TMEL + m0) * TTEXT;
    const int sid = (w - 5) * 64 + lane;           // 0..191
    for (int c = sid; c < 4096; c += 192) {        // f32x4 chunks over 32x512 tile
      const int row = c >> 7, col = (c & 127) << 2;
      u16x4 h4 = *reinterpret_cast<const u16x4*>(&s_attn[row][col]);
      f32x4 a4;
      #pragma unroll
      for (int r = 0; r < 4; ++r) a4[r] = b2f(h4[r]);
      const size_t o = obase + (size_t)row * TTEXT + col;
      st_nt(&out1[o], a4);
      st_nt(&out2[o], a4);
    }
  }
  barrier_lgkm();   // barrier 3: s_cbf visible; s_attn dead (s_o lives here now)

  // ---- output projection: ds_read + register wf only (no vmem loads) ----
  bf16x8 ca[2][3];
  #pragma unroll
  for (int mt = 0; mt < 2; ++mt)
    #pragma unroll
    for (int ks = 0; ks < 3; ++ks)
      ca[mt][ks] = ldb(&s_cbf[mt * 16 + llo][ks * 32 + lhi * 8]);

  #pragma unroll
  for (int nt = 0; nt < 2; ++nt) {
    f32x4 oo[2] = {};
    #pragma unroll
    for (int ks = 0; ks < 3; ++ks) {
      #pragma unroll
      for (int mt = 0; mt < 2; ++mt)
        oo[mt] = __builtin_amdgcn_mfma_f32_16x16x32_bf16(wf[nt][ks], ca[mt][ks], oo[mt], 0, 0, 0);
    }
    f32x4 bo4 = *reinterpret_cast<const f32x4*>(&bo[n0 + nt * 16 + lhi * 4]);
    #pragma unroll
    for (int mt = 0; mt < 2; ++mt) {
      const int row = mt * 16 + llo;
      const int chunk = (w * 8 + nt * 4 + lhi) ^ (row & 7);   // swizzled 16B chunk
      f32x4 res;
      #pragma unroll
      for (int r = 0; r < 4; ++r) res[r] = oo[mt][r] + bo4[r];
      *reinterpret_cast<f32x4*>(&s_o[row * NOUT + chunk * 4]) = res;
    }
  }
  barrier_lgkm();   // barrier 4: s_o visible

  // ---- out0 from LDS, linear order: 1KB fully-coalesced nt stores ----
  const size_t obase0 = ((size_t)b * TMEL + m0) * NOUT;
  #pragma unroll
  for (int it = 0; it < 4; ++it) {
    const int c = tid + it * 512;          // 16B chunk id over 32x256 f32 tile
    const int row = c >> 6, chunk = c & 63;
    const int chunk_sw = chunk ^ (row & 7);
    f32x4 v = *reinterpret_cast<const f32x4*>(&s_o[row * NOUT + chunk_sw * 4]);
    st_nt(&out0[obase0 + (size_t)row * NOUT + chunk * 4], v);
  }
}

extern "C" void kernel_launch(void* const* d_in, const int* in_sizes, int n_in,
                              void* d_out, int out_size, void* d_ws, size_t ws_size,
                              hipStream_t stream)
{
  (void)in_sizes; (void)n_in; (void)out_size; (void)ws_size;
  const float* queries = (const float*)d_in[0];
  const float* keys    = (const float*)d_in[1];
  const float* values  = (const float*)d_in[2];
  const int*   mask    = (const int*)d_in[3];   // bool input -> int32 on device
  const float* prior   = (const float*)d_in[4];
  const float* Wq = (const float*)d_in[5];
  const float* bq = (const float*)d_in[6];
  const float* Wk = (const float*)d_in[7];
  const float* bk = (const float*)d_in[8];
  const float* Wv = (const float*)d_in[9];
  const float* bv = (const float*)d_in[10];
  const float* Wo = (const float*)d_in[11];
  const float* bo = (const float*)d_in[12];

  float* out0 = (float*)d_out;
  float* out1 = out0 + (size_t)BATCH * TMEL * NOUT;
  float* out2 = out1 + (size_t)BATCH * TMEL * TTEXT;

  unsigned short* Kp  = (unsigned short*)d_ws;
  unsigned short* Vt  = Kp  + (size_t)BATCH * TTEXT * DP;
  unsigned short* Wqt = Vt  + (size_t)BATCH * DD * TTEXT;
  unsigned short* Wkt = Wqt + (size_t)DD * DP;
  unsigned short* Wvt = Wkt + (size_t)DD * NK;
  unsigned short* Wot = Wvt + (size_t)DD * NK;

  const float inv_scale = 1.0f / sqrtf((float)DD);   // both q,k scales folded into K

  prep_w_kernel<<<dim3((NOUT * DP + 255) / 256), 256, 0, stream>>>(
      Wq, Wk, Wv, Wo, Wqt, Wkt, Wvt, Wot);
  proj_kv_kernel<<<dim3(2 * BATCH * TTEXT / 16), 64, 0, stream>>>(
      keys, values, Wkt, Wvt, bk, bv, Kp, Vt, inv_scale);
  attn_main_kernel<<<dim3(TMEL / 32, BATCH), 512, 0, stream>>>(
      queries, Wqt, bq, prior, mask, Kp, Vt, Wot, bo, out0, out1, out2);
}